// Round 6
// baseline (217.882 us; speedup 1.0000x reference)
//
#include <hip/hip_runtime.h>

typedef unsigned short u16;
typedef unsigned int u32;
typedef __attribute__((ext_vector_type(8))) short bfrag;   // 8 bf16 (4 VGPRs)
typedef __attribute__((ext_vector_type(4))) float facc;    // 4 fp32

#define N 8192
#define DIM 512
#define BM 128
#define BK 32
#define NK (DIM / BK)             // 16 K-steps
#define NTILE 2080                // 64*65/2 upper-triangular block pairs
#define NPART 64                  // one (m,s) partial per row per block-column
#define NCLS 100
#define TPX 260                   // tiles per XCD chunk (2080/8)

#if __has_builtin(__builtin_amdgcn_exp2f)
#define EXP2(x) __builtin_amdgcn_exp2f(x)
#else
#define EXP2(x) exp2f(x)
#endif

__device__ __forceinline__ u16 f2bf(float f) {            // RNE fp32->bf16
  u32 u = __float_as_uint(f);
  u32 r = u + 0x7fffu + ((u >> 16) & 1u);
  return (u16)(r >> 16);
}
__device__ __forceinline__ float bf2f(u16 h) {
  return __uint_as_float(((u32)h) << 16);
}

// ---- prep: scale by sqrt(log2e/0.035) and split fp32 -> bf16 hi/lo --------
__global__ void prep_kernel(const float* __restrict__ F, u16* __restrict__ Ahi,
                            u16* __restrict__ Alo, float* __restrict__ classSum,
                            int* __restrict__ classCnt)
{
  const float sc = sqrtf(1.4426950408889634f / 0.035f);
  int idx = (blockIdx.x * 256 + threadIdx.x) * 4;
  float4 x = *(const float4*)(F + idx);
  float v[4] = {x.x * sc, x.y * sc, x.z * sc, x.w * sc};
  u16 h[4], l[4];
#pragma unroll
  for (int i = 0; i < 4; ++i) {
    h[i] = f2bf(v[i]);
    l[i] = f2bf(v[i] - bf2f(h[i]));
  }
  *(ushort4*)(Ahi + idx) = make_ushort4(h[0], h[1], h[2], h[3]);
  *(ushort4*)(Alo + idx) = make_ushort4(l[0], l[1], l[2], l[3]);
  if (blockIdx.x == 0 && threadIdx.x < NCLS) {
    classSum[threadIdx.x] = 0.f;
    classCnt[threadIdx.x] = 0;
  }
}

__device__ __forceinline__ void stage16(const u16* g, u16* l) {
  __builtin_amdgcn_global_load_lds((const __attribute__((address_space(1))) void*)g,
                                   (__attribute__((address_space(3))) void*)l, 16, 0, 0);
}

__device__ __forceinline__ void mergeMS(float& m, float& s, float m2, float s2) {
  float M = fmaxf(m, m2);
  s = s * EXP2(m - M) + s2 * EXP2(m2 - M);
  m = M;
}

// ---- main: symmetric flash Gram, 2-phase double-buffered prefetch ---------
// Tile = 128x128 of D (I<=J). BK=32, LDS = 2 x 32KB double buffer.
// Per K-step: issue next step's global_load_lds FIRST, then ds_read+MFMA on
// the current buffer, then ONE vmcnt(0)+barrier (T3-minimum 2-phase; loads
// fly under the 48-MFMA compute).  LDS layout per 8KB tile (round-3 proven,
// 0 bank conflicts): 64 lines x 128B; line L holds rows 2L,2L+1; logical
// chunk cb = (row&1)*4 + kchunk stored at cb ^ (L&7); inverse permutation
// applied on the GLOBAL source address (rule 21 both-sides).
__global__ __launch_bounds__(256, 2) void gram_flash(
    const u16* __restrict__ Ahi, const u16* __restrict__ Alo,
    const int* __restrict__ labels,
    float* __restrict__ m_part, float* __restrict__ s_part)
{
  __shared__ __align__(16) u16 lds[2][4 * BM * BK];   // 2 x 32 KB
  const int tid = threadIdx.x;
  const int wave = tid >> 6;
  const int lane = tid & 63;
  const int wr = wave >> 1, wc = wave & 1;
  const int l15 = lane & 15, lg = lane >> 4;

  // ---- blockIdx -> tile id (XCD-chunked, supertile-major; round-3 proven) --
  const int t = (blockIdx.x & 7) * TPX + (blockIdx.x >> 3);
  int SI = 0, base = 0;
  for (;; ++SI) {                        // supertile row: 36 + (7-SI)*64 tiles
    int rowcnt = 36 + (7 - SI) * 64;
    if (t < base + rowcnt) break;
    base += rowcnt;
  }
  const int r = t - base;
  int SJ, li, lj;
  if (r < 36) {                          // diagonal supertile: 8x8 triangle
    SJ = SI;
    int a = 0, cum = 0;
    for (;; ++a) { if (r < cum + (8 - a)) break; cum += 8 - a; }
    li = a; lj = a + (r - cum);
  } else {                               // off-diagonal supertiles, row-major
    int rr = r - 36;
    SJ = SI + 1 + (rr >> 6);
    li = (rr & 63) >> 3;
    lj = rr & 7;
  }
  const int I = SI * 8 + li, J = SJ * 8 + lj;
  const int i0 = I * BM;
  const int j0 = J * BM;

  // row labels (rows of I), packed 4x8bit per mi
  u32 lr[4];
#pragma unroll
  for (int mi = 0; mi < 4; ++mi) {
    u32 pk = 0;
#pragma unroll
    for (int rg = 0; rg < 4; ++rg) {
      int rr2 = i0 + wr * 64 + mi * 16 + lg * 4 + rg;
      pk |= ((u32)labels[rr2 >> 1] & 0xffu) << (8 * rg);
    }
    lr[mi] = pk;
  }
  // col labels (rows of J)
  int lc[4];
#pragma unroll
  for (int ni = 0; ni < 4; ++ni)
    lc[ni] = labels[(j0 + wc * 64 + ni * 16 + l15) >> 1];

  facc acc[4][4];
#pragma unroll
  for (int a = 0; a < 4; ++a)
#pragma unroll
    for (int b = 0; b < 4; ++b)
      acc[a][b] = (facc){0.f, 0.f, 0.f, 0.f};

  // stage K-step kk into buffer b (8 global_load_lds per wave)
  auto STAGE = [&](int kk, int b) {
    u16* d_ahi = &lds[b][0];
    u16* d_alo = &lds[b][BM * BK];
    u16* d_bhi = &lds[b][2 * BM * BK];
    u16* d_blo = &lds[b][3 * BM * BK];
    const int k0 = kk * BK;
#pragma unroll
    for (int q = 0; q < 2; ++q) {
      const int ci = (wave * 2 + q) * 64 + lane;   // 16B-chunk index 0..511
      const int L = ci >> 3;                       // LDS line
      const int sc2 = ci & 7;                      // stored chunk
      const int cb = sc2 ^ (L & 7);                // logical chunk
      const int row = L * 2 + (cb >> 2);
      const int kc = cb & 3;
      const size_t goffA = (size_t)(i0 + row) * DIM + k0 + kc * 8;
      const size_t goffB = (size_t)(j0 + row) * DIM + k0 + kc * 8;
      const int lbase = (wave * 2 + q) * 512;      // u16 units (wave-uniform)
      stage16(Ahi + goffA, d_ahi + lbase);
      stage16(Alo + goffA, d_alo + lbase);
      stage16(Ahi + goffB, d_bhi + lbase);
      stage16(Alo + goffB, d_blo + lbase);
    }
  };

  STAGE(0, 0);
  asm volatile("s_waitcnt vmcnt(0)" ::: "memory");
  __syncthreads();

  for (int k = 0; k < NK; ++k) {
    const int cur = k & 1;
    if (k + 1 < NK) STAGE(k + 1, cur ^ 1);         // loads fly under compute

    const u16* lb_ahi = &lds[cur][0];
    const u16* lb_alo = &lds[cur][BM * BK];
    const u16* lb_bhi = &lds[cur][2 * BM * BK];
    const u16* lb_blo = &lds[cur][3 * BM * BK];

    bfrag fah[4], fal[4], fbh[4], fbl[4];
#pragma unroll
    for (int mi = 0; mi < 4; ++mi) {
      const int row = wr * 64 + mi * 16 + l15;
      const int L = row >> 1;
      const int cb = ((row & 1) << 2) | lg;
      const int off = L * 64 + (cb ^ (L & 7)) * 8; // u16 units (line=64 u16)
      fah[mi] = *(const bfrag*)(lb_ahi + off);
      fal[mi] = *(const bfrag*)(lb_alo + off);
    }
#pragma unroll
    for (int ni = 0; ni < 4; ++ni) {
      const int row = wc * 64 + ni * 16 + l15;
      const int L = row >> 1;
      const int cb = ((row & 1) << 2) | lg;
      const int off = L * 64 + (cb ^ (L & 7)) * 8;
      fbh[ni] = *(const bfrag*)(lb_bhi + off);
      fbl[ni] = *(const bfrag*)(lb_blo + off);
    }
#pragma unroll
    for (int mi = 0; mi < 4; ++mi)
#pragma unroll
      for (int ni = 0; ni < 4; ++ni)
        acc[mi][ni] = __builtin_amdgcn_mfma_f32_16x16x32_bf16(fah[mi], fbh[ni], acc[mi][ni], 0, 0, 0);
#pragma unroll
    for (int mi = 0; mi < 4; ++mi)
#pragma unroll
      for (int ni = 0; ni < 4; ++ni)
        acc[mi][ni] = __builtin_amdgcn_mfma_f32_16x16x32_bf16(fah[mi], fbl[ni], acc[mi][ni], 0, 0, 0);
#pragma unroll
    for (int mi = 0; mi < 4; ++mi)
#pragma unroll
      for (int ni = 0; ni < 4; ++ni)
        acc[mi][ni] = __builtin_amdgcn_mfma_f32_16x16x32_bf16(fal[mi], fbh[ni], acc[mi][ni], 0, 0, 0);

    asm volatile("s_waitcnt vmcnt(0)" ::: "memory");  // next buffer landed
    __syncthreads();                                  // all waves done w/ cur
  }

  // mask in place: same-class pairs -> -1e30 (exp2 underflows to 0)
#pragma unroll
  for (int mi = 0; mi < 4; ++mi)
#pragma unroll
    for (int rg = 0; rg < 4; ++rg) {
      const int labr = (int)((lr[mi] >> (8 * rg)) & 0xffu);
#pragma unroll
      for (int ni = 0; ni < 4; ++ni)
        if (labr == lc[ni]) acc[mi][ni][rg] = -1e30f;
    }

  // row-side reduction -> (m,s) per row of I over these 64 cols
  float rm[16], rs[16];
#pragma unroll
  for (int mi = 0; mi < 4; ++mi)
#pragma unroll
    for (int rg = 0; rg < 4; ++rg) {
      const int si = mi * 4 + rg;
      float m = -1e20f;
#pragma unroll
      for (int ni = 0; ni < 4; ++ni) m = fmaxf(m, acc[mi][ni][rg]);
      float s = 0.f;
#pragma unroll
      for (int ni = 0; ni < 4; ++ni) s += EXP2(acc[mi][ni][rg] - m);
      rm[si] = m; rs[si] = s;
    }
#pragma unroll
  for (int st = 1; st <= 8; st <<= 1)
#pragma unroll
    for (int si = 0; si < 16; ++si)
      mergeMS(rm[si], rs[si], __shfl_xor(rm[si], st, 64), __shfl_xor(rs[si], st, 64));

  // col-side reduction (symmetry) -> (m,s) per row of J over these 64 rows
  float cm[4], cs[4];
#pragma unroll
  for (int ni = 0; ni < 4; ++ni) {
    float m = -1e20f;
#pragma unroll
    for (int mi = 0; mi < 4; ++mi)
#pragma unroll
      for (int rg = 0; rg < 4; ++rg) m = fmaxf(m, acc[mi][ni][rg]);
    float s = 0.f;
#pragma unroll
    for (int mi = 0; mi < 4; ++mi)
#pragma unroll
      for (int rg = 0; rg < 4; ++rg) s += EXP2(acc[mi][ni][rg] - m);
    cm[ni] = m; cs[ni] = s;
  }
#pragma unroll
  for (int st = 16; st <= 32; st <<= 1)
#pragma unroll
    for (int ni = 0; ni < 4; ++ni)
      mergeMS(cm[ni], cs[ni], __shfl_xor(cm[ni], st, 64), __shfl_xor(cs[ni], st, 64));

  // cross-wave merge via LDS (reuse staging buffer 0)
  float* buf = (float*)&lds[0][0];
  float* RM = buf;            // [2][128]
  float* RS = buf + 256;
  float* CM = buf + 512;
  float* CS = buf + 768;

  __syncthreads();
  if (l15 == 0) {
#pragma unroll
    for (int mi = 0; mi < 4; ++mi)
#pragma unroll
      for (int rg = 0; rg < 4; ++rg) {
        const int idx = wr * 64 + mi * 16 + lg * 4 + rg;
        RM[wc * 128 + idx] = rm[mi * 4 + rg];
        RS[wc * 128 + idx] = rs[mi * 4 + rg];
      }
  }
  if (lg == 0 && I != J) {
#pragma unroll
    for (int ni = 0; ni < 4; ++ni) {
      const int c = wc * 64 + ni * 16 + l15;
      CM[wr * 128 + c] = cm[ni];
      CS[wr * 128 + c] = cs[ni];
    }
  }
  __syncthreads();

  if (tid < 128) {                       // rows of I -> slot J
    float m = RM[tid], s = RS[tid];
    mergeMS(m, s, RM[128 + tid], RS[128 + tid]);
    m_part[(size_t)J * N + i0 + tid] = m;
    s_part[(size_t)J * N + i0 + tid] = s;
  } else if (I != J) {                   // rows of J (cols) -> slot I
    const int c = tid - 128;
    float m = CM[c], s = CS[c];
    mergeMS(m, s, CM[128 + c], CS[128 + c]);
    m_part[(size_t)I * N + j0 + c] = m;
    s_part[(size_t)I * N + j0 + c] = s;
  }
}

// ---- combine the 64 partials per row (4-way p-split), per-class sums ------
__global__ void combine_kernel(const float* __restrict__ m_part,
                               const float* __restrict__ s_part,
                               const int* __restrict__ labels,
                               float* __restrict__ classSum,
                               int* __restrict__ classCnt)
{
  __shared__ float MB[4][64], SB[4][64];
  const int jloc = threadIdx.x & 63;
  const int pc = threadIdx.x >> 6;        // 0..3
  const int j = blockIdx.x * 64 + jloc;
  float M = -1e20f, S = 0.f;
  for (int p = pc * 16; p < pc * 16 + 16; ++p)
    mergeMS(M, S, m_part[(size_t)p * N + j], s_part[(size_t)p * N + j]);
  MB[pc][jloc] = M; SB[pc][jloc] = S;
  __syncthreads();
  if (pc == 0) {
#pragma unroll
    for (int q = 1; q < 4; ++q) mergeMS(M, S, MB[q][jloc], SB[q][jloc]);
    int c = labels[j >> 1];
    atomicAdd(&classSum[c], S);
    atomicAdd(&classCnt[c], 1);
  }
}

// ---- finalize: loss = (1/N) * sum_c cnt_c * log(x_c + 1e-12) --------------
__global__ void final_kernel(const float* __restrict__ classSum,
                             const int* __restrict__ classCnt,
                             float* __restrict__ out)
{
  __shared__ float red[128];
  int t = threadIdx.x;
  float total = 0.f;
  for (int c = 0; c < NCLS; ++c) total += classSum[c];
  float term = 0.f;
  if (t < NCLS) {
    int cnt = classCnt[t];
    if (cnt > 0) {
      float x = (total - classSum[t]) / (float)(N - cnt) + 1e-12f;
      term = (float)cnt * logf(x);
    }
  }
  red[t] = term;
  __syncthreads();
  for (int s = 64; s > 0; s >>= 1) {
    if (t < s) red[t] += red[t + s];
    __syncthreads();
  }
  if (t == 0) out[0] = red[0] / (float)N;
}

extern "C" void kernel_launch(void* const* d_in, const int* in_sizes, int n_in,
                              void* d_out, int out_size, void* d_ws, size_t ws_size,
                              hipStream_t stream)
{
  (void)in_sizes; (void)n_in; (void)out_size; (void)ws_size;
  const float* F = (const float*)d_in[0];
  const int* labels = (const int*)d_in[1];
  float* out = (float*)d_out;

  // ws: Ahi (8MB) | Alo (8MB) | m_part (2MB) | s_part (2MB) | class arrays
  char* ws = (char*)d_ws;
  u16* Ahi = (u16*)ws;
  u16* Alo = (u16*)(ws + (size_t)N * DIM * 2);
  float* m_part = (float*)(ws + (size_t)N * DIM * 4);
  float* s_part = m_part + (size_t)NPART * N;
  float* classSum = s_part + (size_t)NPART * N;
  int* classCnt = (int*)(classSum + NCLS);

  prep_kernel<<<(N * DIM) / 1024, 256, 0, stream>>>(F, Ahi, Alo, classSum, classCnt);
  gram_flash<<<NTILE, 256, 0, stream>>>(Ahi, Alo, labels, m_part, s_part);
  combine_kernel<<<N / 64, 256, 0, stream>>>(m_part, s_part, labels, classSum, classCnt);
  final_kernel<<<1, 128, 0, stream>>>(classSum, classCnt, out);
}

// Round 7
// 216.092 us; speedup vs baseline: 1.0083x; 1.0083x over previous
//
#include <hip/hip_runtime.h>

typedef unsigned short u16;
typedef unsigned int u32;
typedef __attribute__((ext_vector_type(8))) short bfrag;   // 8 bf16 (4 VGPRs)
typedef __attribute__((ext_vector_type(4))) float facc;    // 4 fp32

#define N 8192
#define DIM 512
#define BM 128
#define BK 32
#define NK (DIM / BK)             // 16 K-steps
#define NTILE 2080                // 64*65/2 upper-triangular block pairs
#define NPART 64                  // one (m,s) partial per row per block-column
#define NCLS 100
#define TPX 260                   // tiles per XCD (2080/8)
#define NBLK 1024                 // persistent blocks (4 per CU)

#if __has_builtin(__builtin_amdgcn_exp2f)
#define EXP2(x) __builtin_amdgcn_exp2f(x)
#else
#define EXP2(x) exp2f(x)
#endif

__device__ __forceinline__ u16 f2bf(float f) {            // RNE fp32->bf16
  u32 u = __float_as_uint(f);
  u32 r = u + 0x7fffu + ((u >> 16) & 1u);
  return (u16)(r >> 16);
}
__device__ __forceinline__ float bf2f(u16 h) {
  return __uint_as_float(((u32)h) << 16);
}

// ---- prep: scale by sqrt(log2e/0.035) and split fp32 -> bf16 hi/lo --------
__global__ void prep_kernel(const float* __restrict__ F, u16* __restrict__ Ahi,
                            u16* __restrict__ Alo, float* __restrict__ classSum,
                            int* __restrict__ classCnt)
{
  const float sc = sqrtf(1.4426950408889634f / 0.035f);
  int idx = (blockIdx.x * 256 + threadIdx.x) * 4;
  float4 x = *(const float4*)(F + idx);
  float v[4] = {x.x * sc, x.y * sc, x.z * sc, x.w * sc};
  u16 h[4], l[4];
#pragma unroll
  for (int i = 0; i < 4; ++i) {
    h[i] = f2bf(v[i]);
    l[i] = f2bf(v[i] - bf2f(h[i]));
  }
  *(ushort4*)(Ahi + idx) = make_ushort4(h[0], h[1], h[2], h[3]);
  *(ushort4*)(Alo + idx) = make_ushort4(l[0], l[1], l[2], l[3]);
  if (blockIdx.x == 0 && threadIdx.x < NCLS) {
    classSum[threadIdx.x] = 0.f;
    classCnt[threadIdx.x] = 0;
  }
}

__device__ __forceinline__ void stage16(const u16* g, u16* l) {
  __builtin_amdgcn_global_load_lds((const __attribute__((address_space(1))) void*)g,
                                   (__attribute__((address_space(3))) void*)l, 16, 0, 0);
}

__device__ __forceinline__ void mergeMS(float& m, float& s, float m2, float s2) {
  float M = fmaxf(m, m2);
  s = s * EXP2(m - M) + s2 * EXP2(m2 - M);
  m = M;
}

// ---- main: symmetric flash Gram, persistent blocks, 4 blk/CU --------------
// Round-3-proven core: BK=32, 32KB single-buffer staging, serial
// stage->vmcnt(0)->barrier->compute per K-step (latency hidden by 4 blocks/CU
// per m114).  LDS layout per 8KB tile (0 bank conflicts, rounds 3-6): 64
// lines x 128B; line L holds rows 2L,2L+1; logical chunk cb=(row&1)*4+kchunk
// stored at cb^(L&7); inverse permutation applied on the GLOBAL source addr
// (rule 21 both-sides).  NEW: 1024 persistent blocks, each runs a CONTIGUOUS
// run of 2-3 tiles (per XCD: 4x3 + 124x2 = 260), so runs share I-panels and
// the tail shrinks to one near-solo tile.  Epilogue merge uses a dedicated
// 4KB LDS region (36KB total -> still 4 blocks/CU).
__global__ __launch_bounds__(256, 4) void gram_flash(
    const u16* __restrict__ Ahi, const u16* __restrict__ Alo,
    const int* __restrict__ labels,
    float* __restrict__ m_part, float* __restrict__ s_part)
{
  __shared__ __align__(16) u16 lds[4 * BM * BK];   // 32 KB staging
  __shared__ float mbuf[1024];                     // 4 KB merge scratch
  u16* lds_ahi = lds;
  u16* lds_alo = lds + BM * BK;
  u16* lds_bhi = lds + 2 * BM * BK;
  u16* lds_blo = lds + 3 * BM * BK;

  const int tid = threadIdx.x;
  const int wave = tid >> 6;
  const int lane = tid & 63;
  const int wr = wave >> 1, wc = wave & 1;
  const int l15 = lane & 15, lg = lane >> 4;

  // ---- block -> contiguous tile run (XCD-chunked) ----
  const int x = blockIdx.x & 7;        // XCD (HW round-robin)
  const int lb = blockIdx.x >> 3;      // 0..127 within XCD
  int tstart, tcnt;
  if (lb < 4) { tstart = x * TPX + lb * 3;            tcnt = 3; }
  else        { tstart = x * TPX + 12 + (lb - 4) * 2; tcnt = 2; }

  for (int u = 0; u < tcnt; ++u) {
    const int t = tstart + u;
    // decode t -> (I,J), supertile-major (round-3 proven)
    int SI = 0, base = 0;
    for (;; ++SI) {                      // supertile row: 36 + (7-SI)*64 tiles
      int rowcnt = 36 + (7 - SI) * 64;
      if (t < base + rowcnt) break;
      base += rowcnt;
    }
    const int r = t - base;
    int SJ, li, lj;
    if (r < 36) {                        // diagonal supertile: 8x8 triangle
      SJ = SI;
      int a = 0, cum = 0;
      for (;; ++a) { if (r < cum + (8 - a)) break; cum += 8 - a; }
      li = a; lj = a + (r - cum);
    } else {                             // off-diagonal supertiles, row-major
      int rr = r - 36;
      SJ = SI + 1 + (rr >> 6);
      li = (rr & 63) >> 3;
      lj = rr & 7;
    }
    const int I = SI * 8 + li, J = SJ * 8 + lj;
    const int i0 = I * BM;
    const int j0 = J * BM;

    // row labels (rows of I), packed 4x8bit per mi
    u32 lr[4];
#pragma unroll
    for (int mi = 0; mi < 4; ++mi) {
      u32 pk = 0;
#pragma unroll
      for (int rg = 0; rg < 4; ++rg) {
        int rr2 = i0 + wr * 64 + mi * 16 + lg * 4 + rg;
        pk |= ((u32)labels[rr2 >> 1] & 0xffu) << (8 * rg);
      }
      lr[mi] = pk;
    }
    // col labels (rows of J)
    int lc[4];
#pragma unroll
    for (int ni = 0; ni < 4; ++ni)
      lc[ni] = labels[(j0 + wc * 64 + ni * 16 + l15) >> 1];

    facc acc[4][4];
#pragma unroll
    for (int a = 0; a < 4; ++a)
#pragma unroll
      for (int b = 0; b < 4; ++b)
        acc[a][b] = (facc){0.f, 0.f, 0.f, 0.f};

    for (int kk = 0; kk < DIM; kk += BK) {
      __syncthreads();                   // prev compute (or prev tile) done
#pragma unroll
      for (int q = 0; q < 2; ++q) {
        const int ci = (wave * 2 + q) * 64 + lane; // 16B-chunk index 0..511
        const int L = ci >> 3;                     // LDS line
        const int sc2 = ci & 7;                    // stored chunk
        const int cb = sc2 ^ (L & 7);              // logical chunk
        const int row = L * 2 + (cb >> 2);
        const int kc = cb & 3;
        const size_t goffA = (size_t)(i0 + row) * DIM + kk + kc * 8;
        const size_t goffB = (size_t)(j0 + row) * DIM + kk + kc * 8;
        const int lbase = (wave * 2 + q) * 512;    // u16 units (wave-uniform)
        stage16(Ahi + goffA, lds_ahi + lbase);
        stage16(Alo + goffA, lds_alo + lbase);
        stage16(Ahi + goffB, lds_bhi + lbase);
        stage16(Alo + goffB, lds_blo + lbase);
      }
      asm volatile("s_waitcnt vmcnt(0)" ::: "memory");
      __syncthreads();

      bfrag fah[4], fal[4], fbh[4], fbl[4];
#pragma unroll
      for (int mi = 0; mi < 4; ++mi) {
        const int row = wr * 64 + mi * 16 + l15;
        const int L = row >> 1;
        const int cb = ((row & 1) << 2) | lg;
        const int off = L * 64 + (cb ^ (L & 7)) * 8;
        fah[mi] = *(const bfrag*)(lds_ahi + off);
        fal[mi] = *(const bfrag*)(lds_alo + off);
      }
#pragma unroll
      for (int ni = 0; ni < 4; ++ni) {
        const int row = wc * 64 + ni * 16 + l15;
        const int L = row >> 1;
        const int cb = ((row & 1) << 2) | lg;
        const int off = L * 64 + (cb ^ (L & 7)) * 8;
        fbh[ni] = *(const bfrag*)(lds_bhi + off);
        fbl[ni] = *(const bfrag*)(lds_blo + off);
      }
#pragma unroll
      for (int mi = 0; mi < 4; ++mi)
#pragma unroll
        for (int ni = 0; ni < 4; ++ni)
          acc[mi][ni] = __builtin_amdgcn_mfma_f32_16x16x32_bf16(fah[mi], fbh[ni], acc[mi][ni], 0, 0, 0);
#pragma unroll
      for (int mi = 0; mi < 4; ++mi)
#pragma unroll
        for (int ni = 0; ni < 4; ++ni)
          acc[mi][ni] = __builtin_amdgcn_mfma_f32_16x16x32_bf16(fah[mi], fbl[ni], acc[mi][ni], 0, 0, 0);
#pragma unroll
      for (int mi = 0; mi < 4; ++mi)
#pragma unroll
        for (int ni = 0; ni < 4; ++ni)
          acc[mi][ni] = __builtin_amdgcn_mfma_f32_16x16x32_bf16(fal[mi], fbh[ni], acc[mi][ni], 0, 0, 0);
    }

    // mask in place: same-class pairs -> -1e30 (exp2 underflows to 0)
#pragma unroll
    for (int mi = 0; mi < 4; ++mi)
#pragma unroll
      for (int rg = 0; rg < 4; ++rg) {
        const int labr = (int)((lr[mi] >> (8 * rg)) & 0xffu);
#pragma unroll
        for (int ni = 0; ni < 4; ++ni)
          if (labr == lc[ni]) acc[mi][ni][rg] = -1e30f;
      }

    // row-side reduction -> (m,s) per row of I over these 64 cols
    float rm[16], rs[16];
#pragma unroll
    for (int mi = 0; mi < 4; ++mi)
#pragma unroll
      for (int rg = 0; rg < 4; ++rg) {
        const int si = mi * 4 + rg;
        float m = -1e20f;
#pragma unroll
        for (int ni = 0; ni < 4; ++ni) m = fmaxf(m, acc[mi][ni][rg]);
        float s = 0.f;
#pragma unroll
        for (int ni = 0; ni < 4; ++ni) s += EXP2(acc[mi][ni][rg] - m);
        rm[si] = m; rs[si] = s;
      }
#pragma unroll
    for (int st = 1; st <= 8; st <<= 1)
#pragma unroll
      for (int si = 0; si < 16; ++si)
        mergeMS(rm[si], rs[si], __shfl_xor(rm[si], st, 64), __shfl_xor(rs[si], st, 64));

    // col-side reduction (symmetry) -> (m,s) per row of J over these 64 rows
    float cm[4], cs[4];
#pragma unroll
    for (int ni = 0; ni < 4; ++ni) {
      float m = -1e20f;
#pragma unroll
      for (int mi = 0; mi < 4; ++mi)
#pragma unroll
        for (int rg = 0; rg < 4; ++rg) m = fmaxf(m, acc[mi][ni][rg]);
      float s = 0.f;
#pragma unroll
      for (int mi = 0; mi < 4; ++mi)
#pragma unroll
        for (int rg = 0; rg < 4; ++rg) s += EXP2(acc[mi][ni][rg] - m);
      cm[ni] = m; cs[ni] = s;
    }
#pragma unroll
    for (int st = 16; st <= 32; st <<= 1)
#pragma unroll
      for (int ni = 0; ni < 4; ++ni)
        mergeMS(cm[ni], cs[ni], __shfl_xor(cm[ni], st, 64), __shfl_xor(cs[ni], st, 64));

    // cross-wave merge via dedicated mbuf (no aliasing with staging LDS)
    float* RM = mbuf;            // [2][128]
    float* RS = mbuf + 256;
    float* CM = mbuf + 512;
    float* CS = mbuf + 768;

    __syncthreads();
    if (l15 == 0) {
#pragma unroll
      for (int mi = 0; mi < 4; ++mi)
#pragma unroll
        for (int rg = 0; rg < 4; ++rg) {
          const int idx = wr * 64 + mi * 16 + lg * 4 + rg;
          RM[wc * 128 + idx] = rm[mi * 4 + rg];
          RS[wc * 128 + idx] = rs[mi * 4 + rg];
        }
    }
    if (lg == 0 && I != J) {
#pragma unroll
      for (int ni = 0; ni < 4; ++ni) {
        const int c = wc * 64 + ni * 16 + l15;
        CM[wr * 128 + c] = cm[ni];
        CS[wr * 128 + c] = cs[ni];
      }
    }
    __syncthreads();

    if (tid < 128) {                     // rows of I -> slot J
      float m = RM[tid], s = RS[tid];
      mergeMS(m, s, RM[128 + tid], RS[128 + tid]);
      m_part[(size_t)J * N + i0 + tid] = m;
      s_part[(size_t)J * N + i0 + tid] = s;
    } else if (I != J) {                 // rows of J (cols) -> slot I
      const int c = tid - 128;
      float m = CM[c], s = CS[c];
      mergeMS(m, s, CM[128 + c], CS[128 + c]);
      m_part[(size_t)I * N + j0 + c] = m;
      s_part[(size_t)I * N + j0 + c] = s;
    }
  }
}

// ---- combine the 64 partials per row (4-way p-split), per-class sums ------
__global__ void combine_kernel(const float* __restrict__ m_part,
                               const float* __restrict__ s_part,
                               const int* __restrict__ labels,
                               float* __restrict__ classSum,
                               int* __restrict__ classCnt)
{
  __shared__ float MB[4][64], SB[4][64];
  const int jloc = threadIdx.x & 63;
  const int pc = threadIdx.x >> 6;        // 0..3
  const int j = blockIdx.x * 64 + jloc;
  float M = -1e20f, S = 0.f;
  for (int p = pc * 16; p < pc * 16 + 16; ++p)
    mergeMS(M, S, m_part[(size_t)p * N + j], s_part[(size_t)p * N + j]);
  MB[pc][jloc] = M; SB[pc][jloc] = S;
  __syncthreads();
  if (pc == 0) {
#pragma unroll
    for (int q = 1; q < 4; ++q) mergeMS(M, S, MB[q][jloc], SB[q][jloc]);
    int c = labels[j >> 1];
    atomicAdd(&classSum[c], S);
    atomicAdd(&classCnt[c], 1);
  }
}

// ---- finalize: loss = (1/N) * sum_c cnt_c * log(x_c + 1e-12) --------------
__global__ void final_kernel(const float* __restrict__ classSum,
                             const int* __restrict__ classCnt,
                             float* __restrict__ out)
{
  __shared__ float red[128];
  int t = threadIdx.x;
  float total = 0.f;
  for (int c = 0; c < NCLS; ++c) total += classSum[c];
  float term = 0.f;
  if (t < NCLS) {
    int cnt = classCnt[t];
    if (cnt > 0) {
      float x = (total - classSum[t]) / (float)(N - cnt) + 1e-12f;
      term = (float)cnt * logf(x);
    }
  }
  red[t] = term;
  __syncthreads();
  for (int s = 64; s > 0; s >>= 1) {
    if (t < s) red[t] += red[t + s];
    __syncthreads();
  }
  if (t == 0) out[0] = red[0] / (float)N;
}

extern "C" void kernel_launch(void* const* d_in, const int* in_sizes, int n_in,
                              void* d_out, int out_size, void* d_ws, size_t ws_size,
                              hipStream_t stream)
{
  (void)in_sizes; (void)n_in; (void)out_size; (void)ws_size;
  const float* F = (const float*)d_in[0];
  const int* labels = (const int*)d_in[1];
  float* out = (float*)d_out;

  // ws: Ahi (8MB) | Alo (8MB) | m_part (2MB) | s_part (2MB) | class arrays
  char* ws = (char*)d_ws;
  u16* Ahi = (u16*)ws;
  u16* Alo = (u16*)(ws + (size_t)N * DIM * 2);
  float* m_part = (float*)(ws + (size_t)N * DIM * 4);
  float* s_part = m_part + (size_t)NPART * N;
  float* classSum = s_part + (size_t)NPART * N;
  int* classCnt = (int*)(classSum + NCLS);

  prep_kernel<<<(N * DIM) / 1024, 256, 0, stream>>>(F, Ahi, Alo, classSum, classCnt);
  gram_flash<<<NBLK, 256, 0, stream>>>(Ahi, Alo, labels, m_part, s_part);
  combine_kernel<<<N / 64, 256, 0, stream>>>(m_part, s_part, labels, classSum, classCnt);
  final_kernel<<<1, 128, 0, stream>>>(classSum, classCnt, out);
}